// Round 4
// baseline (766.923 us; speedup 1.0000x reference)
//
#include <hip/hip_runtime.h>

#define EPS 1e-5f

typedef __attribute__((ext_vector_type(4)))  __bf16 bf16x4;
typedef __attribute__((ext_vector_type(8)))  __bf16 bf16x8;
typedef __attribute__((ext_vector_type(4)))  float  f32x4;
typedef __attribute__((ext_vector_type(16))) float  f32x16;

// ============ one-shot weight permutation (ALL mfma conv weights, one dispatch) ======
__device__ inline void wprep_generic(const float* __restrict__ w, __bf16* __restrict__ wA,
                                     int CIN, int KS, int NCHUNK, int i)
{
    const int j    = i & 7;
    const int co   = (i >> 3) & 15;
    const int quad = (i >> 7) & 3;
    const int ch   = (i >> 9) % NCHUNK;
    const int g    = (i >> 9) / NCHUNK;
    const int k    = ch * 32 + quad * 8 + j;
    const int t    = k >> 4, c = k & 15;
    float v = 0.f;
    if (t < KS * KS) v = w[((co * CIN + g * 16 + c) * KS + t / KS) * KS + t % KS];
    wA[i] = (__bf16)v;
}

__global__ __launch_bounds__(256) void k_wprep_all(const float* __restrict__ c1w,
                                                   const float* __restrict__ rgw,
                                                   const float* __restrict__ w2,
                                                   const float* __restrict__ w3,
                                                   const float* __restrict__ w5,
                                                   __bf16* __restrict__ wA1,
                                                   __bf16* __restrict__ wR,
                                                   __bf16* __restrict__ wA2,
                                                   __bf16* __restrict__ wA3,
                                                   __bf16* __restrict__ wA5)
{
    int i = blockIdx.x * 256 + threadIdx.x;
    if (i < 16896) {   // conv1: wA1[(kx*3+c)*512 + half*256 + co*8 + j]
        const int j = i & 7, co = (i >> 3) & 31, hf = (i >> 8) & 1, grp = i >> 9;
        const int kx = grp / 3, c = grp - kx * 3;
        const int k48 = c * 16 + hf * 8 + j, ky = k48 >> 2, ci = k48 & 3;
        wA1[i] = (__bf16)((ci < 3 && ky < 11) ? c1w[((co * 3 + ci) * 11 + ky) * 11 + kx] : 0.f);
        return;
    }
    i -= 16896;
    if (i < 589824) {  // region: wR[reg][tap*1024 + cg*256 + co*8 + j], ci = cg*8+j
        const int reg = i / 9216, q = i - reg * 9216;
        const int j = q & 7, co = (q >> 3) & 31, cg = (q >> 8) & 3, tap = q >> 10;
        const int ci = cg * 8 + j;
        wR[i] = (__bf16)rgw[(size_t)reg * 9216 + co * 288 + ci * 9 + tap];
        return;
    }
    i -= 589824;
    if (i < 32768) { wprep_generic(w2, wA2, 32, 8, 32, i); return; }
    i -= 32768;
    if (i < 16384) { wprep_generic(w3, wA3, 16, 8, 32, i); return; }
    i -= 16384;
    if (i < 6656)  { wprep_generic(w5, wA5, 16, 5, 13, i); }
}

// ============ fused conv1 + region + relu/maxpool/bn2, channel-last pooled out =======
// Weights read from pre-permuted global (L1/L2-hot) -> LDS is act+sx only (33 KB) ->
// 4 blocks/CU. act pixel stride = 40 elems (80 B): all region reads are single 16-B
// aligned ds_read_b128, bank-slot pattern (5*pix mod 8) tiles all banks -> conflict-free.
template <int TH, int TW, int NIMG>
__device__ void fused_body(const float* __restrict__ xg,
                           const __bf16* __restrict__ wA1, const __bf16* __restrict__ wR,
                           const float* __restrict__ c1b,
                           const float* __restrict__ gg, const float* __restrict__ bb,
                           const float* __restrict__ mm, const float* __restrict__ vv,
                           const float* __restrict__ cbp,
                           const float* __restrict__ g2, const float* __restrict__ b2,
                           const float* __restrict__ m2, const float* __restrict__ v2,
                           __bf16* __restrict__ hp,
                           __bf16* act, __bf16* sx, __bf16* zbuf, float* prm,
                           int reg, int n0, int Y0, int X0)
{
    constexpr int C     = TW + 10;
    constexpr int RR    = TH + 10;
    constexpr int SSTR  = 4 * (TH + 11);
    constexpr int NP    = TH * TW;
    constexpr int NPT   = (NP + 31) / 32;
    constexpr int NT    = (NPT + 3) / 4;
    constexpr int PWW   = TW / 2;
    constexpr int TOT   = 3 * RR * C;
    constexpr int NLOAD = (TOT + 255) / 256;
    constexpr int ASTR  = 40;             // act pixel stride (elems) -> 80 B

    const int tid  = threadIdx.x;
    const int lane = tid & 63;
    const int wv   = tid >> 6;
    const int half = lane >> 5;
    const int l31  = lane & 31;
    const int YP = Y0 >> 1, XP = X0 >> 1;

    if (tid < 32) {
        const float sc = gg[reg * 32 + tid] * rsqrtf(vv[reg * 32 + tid] + EPS);
        const float b1 = c1b[tid];
        prm[tid]       = sc;
        prm[32 + tid]  = bb[reg * 32 + tid] - mm[reg * 32 + tid] * sc + sc * b1;
        prm[64 + tid]  = cbp[reg * 32 + tid] + b1;
        const float s2 = g2[tid] * rsqrtf(v2[tid] + EPS);
        prm[96 + tid]  = s2;
        prm[128 + tid] = b2[tid] - m2[tid] * s2;
    }
    for (int i = tid; i < C * SSTR; i += 256) sx[i] = (__bf16)0.f;

    const __bf16* wRr = wR + (size_t)reg * 9216;

    // per-wave pixel tiles, quad-pool mapping
    const int sub = l31 & 3;
    int py[NT], px[NT], yy0[NT], xx0[NT]; bool val[NT];
    #pragma unroll
    for (int t = 0; t < NT; ++t) {
        const int til = wv + t * 4;
        int p = til * 32 + l31;
        val[t] = (til < NPT) && (p < NP);
        if (!val[t]) p = l31;
        const int q = p >> 2;
        py[t] = q / PWW; px[t] = q - py[t] * PWW;
        yy0[t] = 2 * py[t] + ((p & 3) >> 1);
        xx0[t] = 2 * px[t] + (p & 1);
    }

    // prefetch img0 x-slab into registers
    float pf[NLOAD];
    #pragma unroll
    for (int k = 0; k < NLOAD; ++k) {
        const int idx = tid + k * 256;
        float v = 0.f;
        if (idx < TOT) {
            const int col = idx % C, rr = idx / C;
            const int row = rr % RR, ci = rr / RR;
            v = xg[(((size_t)n0 * 3 + ci) * 142 + Y0 + row) * 142 + X0 + col];
        }
        pf[k] = v;
    }
    __syncthreads();

    for (int img = 0; img < NIMG; ++img) {
        const int n = n0 + img;
        #pragma unroll
        for (int k = 0; k < NLOAD; ++k) {
            const int idx = tid + k * 256;
            if (idx < TOT) {
                const int col = idx % C, rr = idx / C;
                const int row = rr % RR, ci = rr / RR;
                sx[col * SSTR + row * 4 + ci] = (__bf16)pf[k];
            }
        }
        __syncthreads();
        if (img + 1 < NIMG) {
            #pragma unroll
            for (int k = 0; k < NLOAD; ++k) {
                const int idx = tid + k * 256;
                if (idx < TOT) {
                    const int col = idx % C, rr = idx / C;
                    const int row = rr % RR, ci = rr / RR;
                    pf[k] = xg[(((size_t)(n + 1) * 3 + ci) * 142 + Y0 + row) * 142 + X0 + col];
                }
            }
        }
        // ---- conv1 (A-frags from global wA1) ----
        f32x16 a1[NT];
        #pragma unroll
        for (int t = 0; t < NT; ++t) a1[t] = (f32x16){};
        for (int kx = 0; kx < 11; ++kx) {
            #pragma unroll
            for (int c = 0; c < 3; ++c) {
                const bf16x8 A = *(const bf16x8*)&wA1[((kx * 3 + c) * 2 + half) * 256 + l31 * 8];
                #pragma unroll
                for (int t = 0; t < NT; ++t) {
                    if (wv + t * 4 < NPT) {
                        const int off = (xx0[t] + kx) * SSTR + (yy0[t] + c * 4 + half * 2) * 4;
                        const bf16x4 lo = *(const bf16x4*)&sx[off];
                        const bf16x4 hi = *(const bf16x4*)&sx[off + 4];
                        a1[t] = __builtin_amdgcn_mfma_f32_32x32x16_bf16(
                                    A, __builtin_shufflevector(lo, hi, 0, 1, 2, 3, 4, 5, 6, 7),
                                    a1[t], 0, 0, 0);
                    }
                }
            }
        }
        // ---- act = bf16(relu(bn1)), stride-40 pixels, b64 packs ----
        #pragma unroll
        for (int t = 0; t < NT; ++t) {
            if (val[t]) {
                const int pix = yy0[t] * TW + xx0[t];
                #pragma unroll
                for (int g = 0; g < 4; ++g) {
                    bf16x4 pk;
                    #pragma unroll
                    for (int j = 0; j < 4; ++j) {
                        const int co = 4 * half + 8 * g + j;
                        pk[j] = (__bf16)fmaxf(a1[t][4 * g + j] * prm[co] + prm[32 + co], 0.f);
                    }
                    *(bf16x4*)&act[pix * ASTR + 8 * g + 4 * half] = pk;
                }
            }
        }
        __syncthreads();
        // ---- region conv (A-frags from global wRr; acc starts at a1 = residual) ----
        f32x16 ar[NT];
        #pragma unroll
        for (int t = 0; t < NT; ++t) ar[t] = a1[t];
        #pragma unroll
        for (int c = 0; c < 18; ++c) {
            const int tap = c >> 1;
            const int ky = tap / 3, kxx = tap - ky * 3;
            const bf16x8 A = *(const bf16x8*)&wRr[(tap * 4 + (c & 1) * 2 + half) * 256 + l31 * 8];
            #pragma unroll
            for (int t = 0; t < NT; ++t) {
                if (wv + t * 4 < NPT) {
                    const int yy = yy0[t] + ky - 1, xx = xx0[t] + kxx - 1;
                    const bool in = ((unsigned)yy < (unsigned)TH) && ((unsigned)xx < (unsigned)TW);
                    const __bf16* src = in ? &act[(yy * TW + xx) * ASTR + (c & 1) * 16 + half * 8] : zbuf;
                    const bf16x8 B = *(const bf16x8*)src;
                    ar[t] = __builtin_amdgcn_mfma_f32_32x32x16_bf16(A, B, ar[t], 0, 0, 0);
                }
            }
        }
        // ---- epilogue: + bias, relu, quad-pool, bn2, channel-last bf16x4 stores ----
        #pragma unroll
        for (int t = 0; t < NT; ++t) {
            if (wv + t * 4 < NPT) {
                float pooled[16];
                #pragma unroll
                for (int r = 0; r < 16; ++r) {
                    const int co = (r & 3) + 8 * (r >> 2) + 4 * half;
                    float v = ar[t][r] + prm[64 + co];
                    v = fmaxf(v, 0.f);
                    v = fmaxf(v, __shfl_xor(v, 1));
                    v = fmaxf(v, __shfl_xor(v, 2));
                    pooled[r] = v;
                }
                if (val[t] && sub == 0) {
                    const size_t base = (((size_t)n * 66 + YP + py[t]) * 66 + XP + px[t]) * 32;
                    #pragma unroll
                    for (int g = 0; g < 4; ++g) {
                        bf16x4 pk;
                        #pragma unroll
                        for (int j = 0; j < 4; ++j) {
                            const int co = 8 * g + 4 * half + j;
                            pk[j] = (__bf16)(pooled[g * 4 + j] * prm[96 + co] + prm[128 + co]);
                        }
                        *(bf16x4*)&hp[base + 8 * g + 4 * half] = pk;
                    }
                }
            }
        }
    }
}

__global__ __launch_bounds__(256, 4) void k_fused(const float* __restrict__ xg,
                                                  const __bf16* __restrict__ wA1,
                                                  const __bf16* __restrict__ wR,
                                                  const float* __restrict__ c1b,
                                                  const float* __restrict__ gg,
                                                  const float* __restrict__ bb,
                                                  const float* __restrict__ mm,
                                                  const float* __restrict__ vv,
                                                  const float* __restrict__ cbp,
                                                  const float* __restrict__ g2,
                                                  const float* __restrict__ b2,
                                                  const float* __restrict__ m2,
                                                  const float* __restrict__ v2,
                                                  __bf16* __restrict__ hp)
{
    __shared__ __align__(16) __bf16 act[12960];   // 324 px * 40
    __shared__ __align__(16) __bf16 sx[3248];     // 28 cols * 116
    __shared__ __align__(16) __bf16 zbuf[8];
    __shared__ float prm[160];
    if (threadIdx.x < 8) zbuf[threadIdx.x] = (__bf16)0.f;
    const int reg = blockIdx.x;
    const int ri = reg >> 3, rj = reg & 7;
    const int n0 = blockIdx.y * 4;
    const int Y0 = ri * 18, X0 = rj * 18;
    if (ri < 7 && rj < 7)
        fused_body<18, 18, 4>(xg, wA1, wR, c1b, gg, bb, mm, vv, cbp, g2, b2, m2, v2, hp,
                              act, sx, zbuf, prm, reg, n0, Y0, X0);
    else if (ri < 7)
        fused_body<18, 6, 4>(xg, wA1, wR, c1b, gg, bb, mm, vv, cbp, g2, b2, m2, v2, hp,
                             act, sx, zbuf, prm, reg, n0, Y0, X0);
    else if (rj < 7)
        fused_body<6, 18, 4>(xg, wA1, wR, c1b, gg, bb, mm, vv, cbp, g2, b2, m2, v2, hp,
                             act, sx, zbuf, prm, reg, n0, Y0, X0);
    else
        fused_body<6, 6, 4>(xg, wA1, wR, c1b, gg, bb, mm, vv, cbp, g2, b2, m2, v2, hp,
                            act, sx, zbuf, prm, reg, n0, Y0, X0);
}

// ============ stride-1 conv + relu via MFMA 16x16x32, COUT=16 ========================
// A-frags from global (no weight LDS). act stride 24 elems -> 16-B aligned b128 reads.
// INCL: channel-last bf16 input (vector staging). OUTCL: channel-last bf16x4 output.
template <typename TIN, typename TOUT, int CIN, int KS, int HIN, int HOUT, int R,
          bool INCL, bool OUTCL>
__global__ __launch_bounds__(256, 4) void k_conv_mfma(const TIN* __restrict__ in,
                                                      const __bf16* __restrict__ wA,
                                                      const float* __restrict__ bias,
                                                      TOUT* __restrict__ out)
{
    constexpr int NG     = CIN / 16;
    constexpr int TAPS   = KS * KS;
    constexpr int NCHUNK = (TAPS * 16 + 31) / 32;
    constexpr int NROWS  = R + KS - 1;
    constexpr int NP     = R * HOUT;
    constexpr int NTIL   = (NP + 15) / 16;
    constexpr int NT     = (NTIL + 3) / 4;
    __shared__ __align__(16) __bf16 act[NROWS * HIN * 24];
    const int tid  = threadIdx.x;
    const int lane = tid & 63;
    const int wv   = tid >> 6;
    const int quad = lane >> 4;
    const int m    = lane & 15;
    const int n    = blockIdx.y;
    int y0 = blockIdx.x * R; if (y0 > HOUT - R) y0 = HOUT - R;

    int yl[NT], xx[NT]; bool val[NT];
    #pragma unroll
    for (int t = 0; t < NT; ++t) {
        const int til = wv + t * 4;
        int p = til * 16 + m;
        val[t] = (til < NTIL) && (p < NP);
        if (!val[t]) p = m;
        yl[t] = p / HOUT; xx[t] = p - yl[t] * HOUT;
    }
    f32x4 acc[NT];
    #pragma unroll
    for (int t = 0; t < NT; ++t) acc[t] = (f32x4){0.f, 0.f, 0.f, 0.f};

    for (int g = 0; g < NG; ++g) {
        if (g) __syncthreads();
        if constexpr (INCL) {
            for (int u = tid; u < NROWS * HIN * 2; u += 256) {
                const int px = u >> 1, hlf = u & 1;
                const int r = px / HIN, xc = px - r * HIN;
                const bf16x8 v = *(const bf16x8*)&in[(((size_t)n * HIN + y0 + r) * HIN + xc) * CIN + g * 16 + hlf * 8];
                *(bf16x8*)&act[px * 24 + hlf * 8] = v;
            }
        } else {
            for (int i = tid; i < 16 * NROWS * HIN; i += 256) {
                const int c = i / (NROWS * HIN), px = i - c * (NROWS * HIN);
                const int r = px / HIN, xc = px - r * HIN;
                act[px * 24 + c] = (__bf16)in[(((size_t)n * CIN + g * 16 + c) * HIN + y0 + r) * HIN + xc];
            }
        }
        __syncthreads();
        for (int ch = 0; ch < NCHUNK; ++ch) {
            const bf16x8 a = *(const bf16x8*)&wA[(size_t)g * NCHUNK * 512 + (ch * 4 + quad) * 128 + m * 8];
            const int kbase = ch * 32 + quad * 8;
            int t = kbase >> 4;
            const int c0 = kbase & 15;
            int ky = 0, kx = 0;
            if (t < TAPS) { ky = t / KS; kx = t - ky * KS; }
            #pragma unroll
            for (int tt = 0; tt < NT; ++tt) {
                const int off = ((yl[tt] + ky) * HIN + xx[tt] + kx) * 24 + c0;
                const bf16x8 b = *(const bf16x8*)&act[off];
                acc[tt] = __builtin_amdgcn_mfma_f32_16x16x32_bf16(a, b, acc[tt], 0, 0, 0);
            }
        }
    }
    #pragma unroll
    for (int tt = 0; tt < NT; ++tt) {
        if (!val[tt]) continue;
        if constexpr (OUTCL) {
            bf16x4 pk;
            #pragma unroll
            for (int r = 0; r < 4; ++r)
                pk[r] = (__bf16)fmaxf(acc[tt][r] + bias[quad * 4 + r], 0.f);
            *(bf16x4*)&out[(((size_t)n * HOUT + y0 + yl[tt]) * HOUT + xx[tt]) * 16 + quad * 4] = pk;
        } else {
            #pragma unroll
            for (int r = 0; r < 4; ++r) {
                const int co = quad * 4 + r;
                out[(((size_t)n * 16 + co) * HOUT + y0 + yl[tt]) * HOUT + xx[tt]]
                    = (TOUT)fmaxf(acc[tt][r] + bias[co], 0.f);
            }
        }
    }
}

// ---------------- strided conv (conv4 only); channel-first f32 in, bf16 out ----------
template <int CIN, int KS, int STRIDE, int HIN, int HOUT>
__global__ __launch_bounds__(256) void k_conv(const float* __restrict__ in,
                                              const float* __restrict__ w,
                                              const float* __restrict__ bias,
                                              __bf16* __restrict__ out)
{
    const int co = blockIdx.y, n = blockIdx.z;
    constexpr int GR  = (HOUT + 3) / 4;
    constexpr int WSZ = CIN * KS * KS;
    constexpr int LEN = KS + 3 * STRIDE;
    __shared__ float ws[WSZ];
    for (int i = threadIdx.x; i < WSZ; i += 256) ws[i] = w[co * WSZ + i];
    __syncthreads();
    const int g = blockIdx.x * 256 + threadIdx.x;
    if (g >= HOUT * GR) return;
    const int y = g / GR;
    int x0 = (g - y * GR) * 4;
    if (x0 > HOUT - 4) x0 = HOUT - 4;
    float a0 = bias[co], a1 = a0, a2 = a0, a3 = a0;
    const float* base = in + (size_t)n * CIN * HIN * HIN;
    for (int ci = 0; ci < CIN; ++ci) {
        for (int ky = 0; ky < KS; ++ky) {
            const float* row = base + ((size_t)ci * HIN + y * STRIDE + ky) * HIN + x0 * STRIDE;
            float r[LEN];
            #pragma unroll
            for (int i = 0; i < LEN; ++i) r[i] = row[i];
            const float* wr = ws + (ci * KS + ky) * KS;
            #pragma unroll
            for (int kx = 0; kx < KS; ++kx) {
                const float wv = wr[kx];
                a0 = fmaf(wv, r[kx],              a0);
                a1 = fmaf(wv, r[kx + STRIDE],     a1);
                a2 = fmaf(wv, r[kx + 2 * STRIDE], a2);
                a3 = fmaf(wv, r[kx + 3 * STRIDE], a3);
            }
        }
    }
    __bf16* o = out + (((size_t)n * 16 + co) * HOUT + y) * HOUT + x0;
    o[0] = (__bf16)fmaxf(a0, 0.f); o[1] = (__bf16)fmaxf(a1, 0.f);
    o[2] = (__bf16)fmaxf(a2, 0.f); o[3] = (__bf16)fmaxf(a3, 0.f);
}

// ---------------- fc GEMM: C[64][N] += A[64][K] * W[N][K]^T, LDS-tiled, split-K ------
__global__ __launch_bounds__(256) void k_fc2(const float* __restrict__ A,
                                             const float* __restrict__ W,
                                             float* __restrict__ C,
                                             int N, int K, int kchunk)
{
    __shared__ float As[64][68];
    __shared__ float Bs[64][132];
    const int n0 = blockIdx.x * 128;
    const int kbeg = blockIdx.y * kchunk;
    const int tid = threadIdx.x;
    const int tm = tid >> 4, tn = tid & 15;
    const int am = tid >> 2, ac = tid & 3;
    const int bn = tid >> 1, bh = tid & 1;
    float acc[4][8] = {};
    for (int k0 = kbeg; k0 < kbeg + kchunk; k0 += 64) {
        #pragma unroll
        for (int q = 0; q < 4; ++q) {
            const int kk = ac * 16 + q * 4;
            const float4 v = *(const float4*)&A[(size_t)am * K + k0 + kk];
            As[kk + 0][am] = v.x; As[kk + 1][am] = v.y;
            As[kk + 2][am] = v.z; As[kk + 3][am] = v.w;
        }
        const int nn = n0 + bn;
        if (nn < N) {
            #pragma unroll
            for (int q = 0; q < 8; ++q) {
                const int kk = bh * 32 + q * 4;
                const float4 v = *(const float4*)&W[(size_t)nn * K + k0 + kk];
                Bs[kk + 0][bn] = v.x; Bs[kk + 1][bn] = v.y;
                Bs[kk + 2][bn] = v.z; Bs[kk + 3][bn] = v.w;
            }
        }
        __syncthreads();
        #pragma unroll 4
        for (int kk = 0; kk < 64; ++kk) {
            float a[4], b[8];
            #pragma unroll
            for (int i = 0; i < 4; ++i) a[i] = As[kk][tm * 4 + i];
            #pragma unroll
            for (int j = 0; j < 8; ++j) b[j] = Bs[kk][tn * 8 + j];
            #pragma unroll
            for (int i = 0; i < 4; ++i)
                #pragma unroll
                for (int j = 0; j < 8; ++j)
                    acc[i][j] = fmaf(a[i], b[j], acc[i][j]);
        }
        __syncthreads();
    }
    #pragma unroll
    for (int i = 0; i < 4; ++i) {
        const int mi = tm * 4 + i;
        #pragma unroll
        for (int j = 0; j < 8; ++j) {
            const int nn = n0 + tn * 8 + j;
            if (nn < N) atomicAdd(&C[(size_t)mi * N + nn], acc[i][j]);
        }
    }
}

__global__ __launch_bounds__(256) void k_bias_act(const float* __restrict__ C,
                                                  const float* __restrict__ bias,
                                                  float* __restrict__ out,
                                                  int N, int total, int relu)
{
    const int i = blockIdx.x * 256 + threadIdx.x;
    if (i >= total) return;
    float v = C[i] + bias[i % N];
    if (relu) v = fmaxf(v, 0.f);
    out[i] = v;
}

extern "C" void kernel_launch(void* const* d_in, const int* in_sizes, int n_in,
                              void* d_out, int out_size, void* d_ws, size_t ws_size,
                              hipStream_t stream)
{
    (void)in_sizes; (void)n_in; (void)out_size; (void)ws_size;
    const float* x       = (const float*)d_in[0];
    const float* conv1_w = (const float*)d_in[1];
    const float* conv1_b = (const float*)d_in[2];
    const float* rg_g    = (const float*)d_in[3];
    const float* rg_b    = (const float*)d_in[4];
    const float* rg_m    = (const float*)d_in[5];
    const float* rg_v    = (const float*)d_in[6];
    const float* rg_w    = (const float*)d_in[7];
    const float* rg_cb   = (const float*)d_in[8];
    const float* bn2_g   = (const float*)d_in[9];
    const float* bn2_b   = (const float*)d_in[10];
    const float* bn2_m   = (const float*)d_in[11];
    const float* bn2_v   = (const float*)d_in[12];
    const float* conv2_w = (const float*)d_in[13];
    const float* conv2_b = (const float*)d_in[14];
    const float* conv3_w = (const float*)d_in[15];
    const float* conv3_b = (const float*)d_in[16];
    const float* conv4_w = (const float*)d_in[17];
    const float* conv4_b = (const float*)d_in[18];
    const float* conv5_w = (const float*)d_in[19];
    const float* conv5_b = (const float*)d_in[20];
    const float* fc1_w   = (const float*)d_in[21];
    const float* fc1_b   = (const float*)d_in[22];
    const float* fc2_w   = (const float*)d_in[23];
    const float* fc2_b   = (const float*)d_in[24];
    const float* fc3_w   = (const float*)d_in[25];
    const float* fc3_b   = (const float*)d_in[26];

    float* ws = (float*)d_ws;
    __bf16* hp  = (__bf16*)ws;                       // (64,66,66,32) CL bf16 = 4,460,544 f
    __bf16* wA1 = (__bf16*)(ws + 4460544);           // 16,896 bf16 = 8,448 f
    __bf16* wR  = (__bf16*)(ws + 4468992);           // 589,824 bf16 = 294,912 f
    __bf16* wA2 = (__bf16*)(ws + 4763904);           // 32,768 bf16 = 16,384 f
    __bf16* wA3 = (__bf16*)(ws + 4780288);           // 16,384 bf16 = 8,192 f
    __bf16* wA5 = (__bf16*)(ws + 4788480);           // 6,656 bf16 = 3,328 f
    __bf16* h3  = (__bf16*)(ws + 4791808);           // (64,59,59,16) CL bf16 = 1,782,272 f
    float*  h4  = ws + 6574080;                      // (64,16,52,52) CF f32 = 2,768,896 f
    __bf16* h5  = (__bf16*)(ws + 9342976);           // (64,16,24,24) CF bf16 = 294,912 f
    float*  h6  = ws + 9637888;                      // conv5 out f32 == fc1 input (64,6400)
    float*  f1  = ws + 10047488;                     // fc1 out (64,4096)
    float*  f2  = ws + 10309632;                     // fc2 out (64,2048)
    float*  f3  = ws + 10440704;                     // fc3 tmp (64,12)

    k_wprep_all<<<dim3(2588), 256, 0, stream>>>(conv1_w, rg_w, conv2_w, conv3_w, conv5_w,
                                                wA1, wR, wA2, wA3, wA5);

    k_fused<<<dim3(64, 16), 256, 0, stream>>>(x, wA1, wR, conv1_b,
                                              rg_g, rg_b, rg_m, rg_v, rg_cb,
                                              bn2_g, bn2_b, bn2_m, bn2_v, hp);

    k_conv_mfma<__bf16, __bf16, 32, 8, 66, 59, 4, true,  true ><<<dim3(15, 64), 256, 0, stream>>>(hp, wA2, conv2_b, h3);
    k_conv_mfma<__bf16, float,  16, 8, 59, 52, 4, true,  false><<<dim3(13, 64), 256, 0, stream>>>(h3, wA3, conv3_b, h4);
    k_conv<16, 6, 2, 52, 24><<<dim3(1, 16, 64), 256, 0, stream>>>(h4, conv4_w, conv4_b, h5);
    k_conv_mfma<__bf16, float,  16, 5, 24, 20, 5, false, false><<<dim3(4, 64), 256, 0, stream>>>(h5, wA5, conv5_b, h6);

    hipMemsetAsync(f1, 0, 262144 * sizeof(float), stream);
    k_fc2<<<dim3(32, 10), 256, 0, stream>>>(h6, fc1_w, f1, 4096, 6400, 640);
    k_bias_act<<<dim3((262144 + 255) / 256), 256, 0, stream>>>(f1, fc1_b, f1, 4096, 262144, 1);

    hipMemsetAsync(f2, 0, 131072 * sizeof(float), stream);
    k_fc2<<<dim3(16, 16), 256, 0, stream>>>(f1, fc2_w, f2, 2048, 4096, 256);
    k_bias_act<<<dim3((131072 + 255) / 256), 256, 0, stream>>>(f2, fc2_b, f2, 2048, 131072, 1);

    hipMemsetAsync(f3, 0, 768 * sizeof(float), stream);
    k_fc2<<<dim3(1, 16), 256, 0, stream>>>(f2, fc3_w, f3, 12, 2048, 128);
    k_bias_act<<<dim3(3), 256, 0, stream>>>(f3, fc3_b, (float*)d_out, 12, 768, 0);
}